// Round 6
// baseline (600.681 us; speedup 1.0000x reference)
//
#include <hip/hip_runtime.h>
#include <math.h>

#define PI_D 3.141592653589793238462643383279502884
#define PI_F 3.14159265358979323846f
#define SCALING_F (1.0f/12.0f)

// off[l] = sum_{j<l}(2j+1)^2
__constant__ int c_OFF[17] = {0,1,10,35,84,165,286,455,680,969,1330,1771,2300,2925,3654,4495,5456};
// cumulative blocks for k_z: per l: ceil(d/4)*d
__constant__ int c_Z4[17] = {0,1,4,14,28,55,88,140,200,285,380,506,644,819,1008,1240,1488};

__device__ __forceinline__ void s_to_lmn(int s, int& l, int& m, int& n) {
    int ll = 15;
    while (s < c_OFF[ll]) --ll;
    int r = s - c_OFF[ll];
    int d = 2*ll + 1;
    l = ll;
    m = r / d - ll;
    n = r % d - ll;
}

// parallel table build: thread i (<64) fills entry i
__device__ __forceinline__ void build_tables_par(double beta, double* lf, double* cp, double* sp) {
    if (threadIdx.x < 64) {
        int i = threadIdx.x;
        lf[i] = lgamma((double)(i + 1));           // log(i!)
        double cb = cos(beta*0.5), sb = sin(beta*0.5);
        cp[i] = (i == 0) ? 1.0 : exp((double)i * log(cb));
        sp[i] = (i == 0) ? 1.0 : exp((double)i * log(sb));
    }
}

__device__ double wigner_d_dev(int l, int m, int n,
                               const double* lf, const double* cp, const double* sp) {
    int kmin = m - n; if (kmin < 0) kmin = 0;
    int kmax = l + m; { int k2 = l - n; if (k2 < kmax) kmax = k2; }
    double pref = 0.5*(lf[l+m] + lf[l-m] + lf[l+n] + lf[l-n]);
    double acc = 0.0;
    for (int k = kmin; k <= kmax; ++k) {
        double lg = pref - (lf[k] + lf[l+m-k] + lf[l-n-k] + lf[n-m+k]);
        double t = exp(lg) * cp[2*l + m - n - 2*k] * sp[n - m + 2*k];
        acc += (k & 1) ? -t : t;
    }
    return acc;
}

// ---- Wigner tables (transposed: W[j][s] for coalesced consumer reads) ----
__global__ void __launch_bounds__(256) k_wigner_in(float* WanT) {
    __shared__ double lf[64], cp[64], sp[64];
    __shared__ double tsum[32];
    __shared__ double wq;
    int j = blockIdx.x >> 2;        // 0..63
    int chunk = blockIdx.x & 3;
    double beta = PI_D * (2*j + 1) / 128.0;   // 4*B_IN = 128
    build_tables_par(beta, lf, cp, sp);
    if (threadIdx.x >= 64 && threadIdx.x < 96) {
        int k = threadIdx.x - 64;
        tsum[k] = sin((double)(2*j+1)*(2*k+1)*PI_D/128.0) / (double)(2*k+1);
    }
    __syncthreads();
    if (threadIdx.x == 0) {
        double inner = 0.0;
        for (int k = 0; k < 32; ++k) inner += tsum[k];
        wq = (2.0/32.0) * sin(PI_D*(2*j+1)/128.0) * inner / 4096.0; // /(2b)^2
    }
    __syncthreads();
    int s0 = chunk*1364, s1 = s0 + 1364; if (s1 > 5456) s1 = 5456;
    for (int s = s0 + threadIdx.x; s < s1; s += 256) {
        int l, m, n; s_to_lmn(s, l, m, n);
        WanT[j*5456 + s] = (float)(wigner_d_dev(l, m, n, lf, cp, sp) * wq);
    }
}

__global__ void __launch_bounds__(256) k_wigner_out(float* WsyT) {
    __shared__ double lf[64], cp[64], sp[64];
    int j = blockIdx.x >> 2;        // 0..31
    int chunk = blockIdx.x & 3;
    build_tables_par(PI_D*(2*j+1)/64.0, lf, cp, sp); // 4*B_OUT=64
    __syncthreads();
    int s0 = chunk*1364, s1 = s0 + 1364; if (s1 > 5456) s1 = 5456;
    for (int s = s0 + threadIdx.x; s < s1; s += 256) {
        int l, m, n; s_to_lmn(s, l, m, n);
        WsyT[j*5456 + s] = (float)(wigner_d_dev(l, m, n, lf, cp, sp) * (double)(2*l+1));
    }
}

__global__ void __launch_bounds__(256) k_wigner_grid(const float* ge, float2* D) {
    __shared__ double lf[64], cp[64], sp[64];
    int g = blockIdx.x >> 2;        // 0..71
    int chunk = blockIdx.x & 3;
    double beta = (double)ge[g*3 + 1];
    double alp  = (double)ge[g*3 + 0];
    double gam  = (double)ge[g*3 + 2];
    build_tables_par(beta, lf, cp, sp);
    __syncthreads();
    int s0 = chunk*1364, s1 = s0 + 1364; if (s1 > 5456) s1 = 5456;
    for (int s = s0 + threadIdx.x; s < s1; s += 256) {
        int l, m, n; s_to_lmn(s, l, m, n);
        double dv = wigner_d_dev(l, m, n, lf, cp, sp);
        double th = m*alp + n*gam;
        double sn, cs; sincos(th, &sn, &cs);
        D[s*72 + g] = make_float2((float)(dv*cs), (float)(-dv*sn));
    }
}

// ---- yc[s][io] = SCALING * sum_g kernel[io][g] * D[s][g]; 4 s per block ----
__global__ void __launch_bounds__(256) k_yc(const float* kern, const float2* D, float2* yc) {
    __shared__ float2 Ds[4][72];
    int s0 = blockIdx.x * 4;
    for (int t = threadIdx.x; t < 288; t += 256) {
        int ss = t / 72, g = t - ss*72;
        Ds[ss][g] = D[(size_t)(s0 + ss)*72 + g];
    }
    __syncthreads();
    for (int io = threadIdx.x; io < 512; io += 256) {
        const float* kp = kern + io*72;
        float2 a0 = {0,0}, a1 = {0,0}, a2 = {0,0}, a3 = {0,0};
        for (int g = 0; g < 72; ++g) {
            float kv = kp[g];
            a0.x = fmaf(kv, Ds[0][g].x, a0.x); a0.y = fmaf(kv, Ds[0][g].y, a0.y);
            a1.x = fmaf(kv, Ds[1][g].x, a1.x); a1.y = fmaf(kv, Ds[1][g].y, a1.y);
            a2.x = fmaf(kv, Ds[2][g].x, a2.x); a2.y = fmaf(kv, Ds[2][g].y, a2.y);
            a3.x = fmaf(kv, Ds[3][g].x, a3.x); a3.y = fmaf(kv, Ds[3][g].y, a3.y);
        }
        yc[(size_t)(s0+0)*512 + io] = make_float2(a0.x*SCALING_F, a0.y*SCALING_F);
        yc[(size_t)(s0+1)*512 + io] = make_float2(a1.x*SCALING_F, a1.y*SCALING_F);
        yc[(size_t)(s0+2)*512 + io] = make_float2(a2.x*SCALING_F, a2.y*SCALING_F);
        yc[(size_t)(s0+3)*512 + io] = make_float2(a3.x*SCALING_F, a3.y*SCALING_F);
    }
}

// ---- forward 2D partial DFT per (b,f,j): Fx[bf][j][mm 0..30][nn 0..15] ----
// v4: stage 1 rewritten as radix-4 DIF (g = g1 + 16*g2). Old direct form was
// LDS-pipe-bound: 5 LDS ops / 16 FMA (160 LDS ops/thread). New: y_r[g1] built
// once in 64 named registers (96 adds), then 4 twiddle-row passes: 64 LDS ops,
// ~290 FMA (2.5x fewer LDS, 1.8x fewer FMA). y0,y2 real; y3 = conj(y1).
#define FFT_YD(I) float y0_##I, y2_##I, y1r_##I, y1i_##I;
#define FFT_YD_ALL FFT_YD(0) FFT_YD(1) FFT_YD(2) FFT_YD(3) FFT_YD(4) FFT_YD(5) \
    FFT_YD(6) FFT_YD(7) FFT_YD(8) FFT_YD(9) FFT_YD(10) FFT_YD(11) FFT_YD(12) \
    FFT_YD(13) FFT_YD(14) FFT_YD(15)
#define FFT_YB(E,O) { \
    float2 xa = *(const float2*)&xs[a][E]; \
    float2 xb = *(const float2*)&xs[a][(E)+16]; \
    float2 xc2 = *(const float2*)&xs[a][(E)+32]; \
    float2 xd = *(const float2*)&xs[a][(E)+48]; \
    float s02 = xa.x + xc2.x, d02 = xa.x - xc2.x; \
    float s13 = xb.x + xd.x, d13 = xb.x - xd.x; \
    y0_##E = s02 + s13; y2_##E = s02 - s13; y1r_##E = d02; y1i_##E = -d13; \
    s02 = xa.y + xc2.y; d02 = xa.y - xc2.y; \
    s13 = xb.y + xd.y; d13 = xb.y - xd.y; \
    y0_##O = s02 + s13; y2_##O = s02 - s13; y1r_##O = d02; y1i_##O = -d13; \
}
#define FFT_A0(E,O) { float4 w = *(const float4*)&t0[E]; \
    c0.x = fmaf(y0_##E, w.x, c0.x); c0.y = fmaf(y0_##E, w.y, c0.y); \
    c0.x = fmaf(y0_##O, w.z, c0.x); c0.y = fmaf(y0_##O, w.w, c0.y); }
#define FFT_A2(E,O) { float4 w = *(const float4*)&t2[E]; \
    c2.x = fmaf(y2_##E, w.x, c2.x); c2.y = fmaf(y2_##E, w.y, c2.y); \
    c2.x = fmaf(y2_##O, w.z, c2.x); c2.y = fmaf(y2_##O, w.w, c2.y); }
#define FFT_A1(E,O) { float4 w = *(const float4*)&t1[E]; \
    c1.x = fmaf(y1r_##E, w.x, c1.x); c1.x = fmaf(-y1i_##E, w.y, c1.x); \
    c1.y = fmaf(y1r_##E, w.y, c1.y); c1.y = fmaf(y1i_##E, w.x, c1.y); \
    c1.x = fmaf(y1r_##O, w.z, c1.x); c1.x = fmaf(-y1i_##O, w.w, c1.x); \
    c1.y = fmaf(y1r_##O, w.w, c1.y); c1.y = fmaf(y1i_##O, w.z, c1.y); }
#define FFT_A3(E,O) { float4 w = *(const float4*)&t3[E]; \
    c3.x = fmaf(y1r_##E, w.x, c3.x); c3.x = fmaf(y1i_##E, w.y, c3.x); \
    c3.y = fmaf(y1r_##E, w.y, c3.y); c3.y = fmaf(-y1i_##E, w.x, c3.y); \
    c3.x = fmaf(y1r_##O, w.z, c3.x); c3.x = fmaf(y1i_##O, w.w, c3.x); \
    c3.y = fmaf(y1r_##O, w.w, c3.y); c3.y = fmaf(-y1i_##O, w.z, c3.y); }
#define FFT_PAIRS(X) X(0,1) X(2,3) X(4,5) X(6,7) X(8,9) X(10,11) X(12,13) X(14,15)

__global__ void __launch_bounds__(256) k_fft(const float* x, float2* Fx) {
    __shared__ float  xs[64][66];    // pad 66: 2-way banks, 8B-aligned rows
    __shared__ float2 T1s[16][66];   // [nn][a], pad 66: 16B-aligned, distinct banks
    __shared__ float2 tw2[16][66];   // tw2[n][g]=e^{-2pi i n g/64}; pad 66
    int blk = blockIdx.x;            // bf*64 + j
    int bf = blk >> 6, j = blk & 63;
    const float* xp = x + (size_t)bf*262144 + j*64;  // x[b,f,a,j,g]
    for (int t = threadIdx.x; t < 1024; t += 256) {
        int a = t >> 4, g4 = (t & 15) << 2;
        float4 v = *(const float4*)(xp + (size_t)a*4096 + g4);
        *(float2*)&xs[a][g4]     = make_float2(v.x, v.y);
        *(float2*)&xs[a][g4 + 2] = make_float2(v.z, v.w);
    }
    for (int t = threadIdx.x; t < 1024; t += 256) {
        int n = t >> 6, g = t & 63;
        float sn, cs;
        sincosf(-2.0f*PI_F*(float)((n*g) & 63)/64.0f, &sn, &cs);
        tw2[n][g] = make_float2(cs, sn);
    }
    __syncthreads();
    // stage 1 (radix-4 DIF): T1[n] = sum_{g1<16} tw2[n][g1] * y_{n&3}[g1]
    {
        int a  = threadIdx.x & 63;
        int n0 = (threadIdx.x >> 6) << 2;
        FFT_YD_ALL
        FFT_PAIRS(FFT_YB)
        float2 c0 = {0,0}, c1 = {0,0}, c2 = {0,0}, c3 = {0,0};
        const float2* t0 = tw2[n0];
        const float2* t1 = tw2[n0 + 1];
        const float2* t2 = tw2[n0 + 2];
        const float2* t3 = tw2[n0 + 3];
        FFT_PAIRS(FFT_A0)
        FFT_PAIRS(FFT_A1)
        FFT_PAIRS(FFT_A2)
        FFT_PAIRS(FFT_A3)
        T1s[n0    ][a] = c0;
        T1s[n0 + 1][a] = c1;
        T1s[n0 + 2][a] = c2;
        T1s[n0 + 3][a] = c3;
    }
    __syncthreads();
    // stage 2: Fx[mm][nn] = sum_a T1[nn][a] e^{-2pi i (mm-15) a/64}; thread = (nn, 2mm)
    {
        int nn = threadIdx.x & 15, mmg = threadIdx.x >> 4;
        int mm0 = mmg*2, mm1 = mm0 + 1;
        int am0 = mm0 >= 15 ? mm0 - 15 : 15 - mm0;
        int am1 = mm1 >= 15 ? mm1 - 15 : 15 - mm1;
        if (am1 > 15) am1 = 15;                 // pad slot mm=31, discarded
        float sg0 = mm0 >= 15 ? 1.f : -1.f;     // conj for negative m
        float sg1 = mm1 >= 15 ? 1.f : -1.f;
        float2 c0 = {0,0}, c1 = {0,0};
        for (int a = 0; a < 64; a += 2) {
            float4 t01 = *(const float4*)&T1s[nn][a];     // T1[a], T1[a+1]
            float4 wa  = *(const float4*)&tw2[am0][a];    // rows 8..15: distinct bank groups
            float4 wb  = *(const float4*)&tw2[am1][a];
            float way0 = wa.y*sg0, way1 = wa.w*sg0;
            float wby0 = wb.y*sg1, wby1 = wb.w*sg1;
            c0.x += t01.x*wa.x - t01.y*way0;
            c0.y += t01.x*way0 + t01.y*wa.x;
            c0.x += t01.z*wa.z - t01.w*way1;
            c0.y += t01.z*way1 + t01.w*wa.z;
            c1.x += t01.x*wb.x - t01.y*wby0;
            c1.y += t01.x*wby0 + t01.y*wb.x;
            c1.x += t01.z*wb.z - t01.w*wby1;
            c1.y += t01.z*wby1 + t01.w*wb.z;
        }
        float2* outp = Fx + (size_t)blk*496;
        outp[mm0*16 + nn] = c0;
        if (mm1 < 31) outp[mm1*16 + nn] = c1;
    }
}

// ---- xc[s][bf] = sum_j WanT[j][s] * F(m(s),n(s)); block = (bf, mm) ----
__global__ void __launch_bounds__(256) k_xc(const float2* Fx, const float* WanT, float2* xc) {
    __shared__ float2 Fsh[31][65];   // [n+15][j]
    int blk = blockIdx.x;            // bf*31 + mm
    int bf = blk / 31, mm = blk - bf*31;
    int m = mm - 15;
    const float2* fp = Fx + (size_t)bf * 64 * 496;
    for (int t = threadIdx.x; t < 1024; t += 256) {   // n >= 0 from slice mm
        int j = t >> 4, nn = t & 15;
        Fsh[nn + 15][j] = fp[j*496 + mm*16 + nn];
    }
    for (int t = threadIdx.x; t < 1024; t += 256) {   // n < 0: conj of slice 30-mm
        int j = t >> 4, nn = t & 15;
        if (nn > 0) {
            float2 v = fp[j*496 + (30 - mm)*16 + nn];
            Fsh[15 - nn][j] = make_float2(v.x, -v.y);
        }
    }
    __syncthreads();
    int am = m < 0 ? -m : m;
    int q = threadIdx.x;
    int l = am;
    while (l <= 15 && q >= 2*l + 1) { q -= 2*l + 1; ++l; }
    if (l <= 15) {
        int n = q - l;
        int d = 2*l + 1;
        int s = c_OFF[l] + (m + l)*d + (n + l);
        const float* wp = WanT + s;
        const float2* frow = Fsh[n + 15];
        float ar = 0.f, ai = 0.f;
        for (int j2 = 0; j2 < 64; ++j2) {
            float w = wp[(size_t)j2*5456];
            ar = fmaf(w, frow[j2].x, ar);
            ai = fmaf(w, frow[j2].y, ai);
        }
        xc[(size_t)s*128 + bf] = make_float2(ar, ai);
    }
}

// ---- per-l complex GEMM: z[(m,b),(n,o)] = sum_{k,i} X[(m,b),(k,i)] Y[(k,i),(n,o)] ----
__global__ void __launch_bounds__(256) k_z(const float2* xc, const float2* yc, float2* zc) {
    __shared__ float2 Ash[2][16][34];   // [buf][i][mb(32)+pad]
    __shared__ float2 Bsh[2][512];      // [buf][io]
    int blk = 1487 - blockIdx.x;        // heavy l first
    int l = 0;
    while (l < 15 && blk >= c_Z4[l+1]) ++l;
    int r = blk - c_Z4[l];
    int d = 2*l + 1;
    int mt = r / d;
    int n0 = r - mt*d;
    int m0 = mt*4;
    int off = c_OFF[l];

    int tx = threadIdx.x & 15, ty = threadIdx.x >> 4;   // ty 0..15
    int o0 = tx*2;

    // staging: thread loads one float4 of A (2 consecutive bf of its row) + one of B
    int mloc_s = threadIdx.x >> 6;            // 0..3
    int bf0    = (threadIdx.x & 63) << 1;     // 0,2,...,126 (even: both halves same b)
    int bs     = bf0 >> 4;                    // b 0..7
    int i0s    = bf0 & 15;                    // even i
    int mbs    = mloc_s*8 + bs;
    int mrow_s = m0 + mloc_s; if (mrow_s > d-1) mrow_s = d-1;
    const float2* xrow = xc + (size_t)(off + mrow_s*d)*128 + bf0;   // k stride: +128
    int io0 = threadIdx.x * 2;
    const float2* yrow = yc + (size_t)(off + n0)*512 + io0;         // k stride: +d*512

    float4 apf, bpf;
    apf = *(const float4*)(xrow);
    bpf = *(const float4*)(yrow);
    Ash[0][i0s+0][mbs] = make_float2(apf.x, apf.y);
    Ash[0][i0s+1][mbs] = make_float2(apf.z, apf.w);
    *(float4*)&Bsh[0][io0] = bpf;
    __syncthreads();

    float2 acc00 = {0.f,0.f}, acc01 = {0.f,0.f}, acc10 = {0.f,0.f}, acc11 = {0.f,0.f};

    for (int k = 0; k < d; ++k) {
        int cur = k & 1;
        if (k + 1 < d) {
            apf = *(const float4*)(xrow + (size_t)(k+1)*128);
            bpf = *(const float4*)(yrow + (size_t)(k+1)*d*512);
        }
        #pragma unroll
        for (int i = 0; i < 16; ++i) {
            float4 a01 = *(const float4*)&Ash[cur][i][ty*2];      // mb=2ty, 2ty+1
            float4 b01 = *(const float4*)&Bsh[cur][i*32 + o0];    // o=o0, o0+1
            acc00.x = fmaf( a01.x, b01.x, acc00.x);
            acc00.x = fmaf(-a01.y, b01.y, acc00.x);
            acc00.y = fmaf( a01.x, b01.y, acc00.y);
            acc00.y = fmaf( a01.y, b01.x, acc00.y);
            acc01.x = fmaf( a01.x, b01.z, acc01.x);
            acc01.x = fmaf(-a01.y, b01.w, acc01.x);
            acc01.y = fmaf( a01.x, b01.w, acc01.y);
            acc01.y = fmaf( a01.y, b01.z, acc01.y);
            acc10.x = fmaf( a01.z, b01.x, acc10.x);
            acc10.x = fmaf(-a01.w, b01.y, acc10.x);
            acc10.y = fmaf( a01.z, b01.y, acc10.y);
            acc10.y = fmaf( a01.w, b01.x, acc10.y);
            acc11.x = fmaf( a01.z, b01.z, acc11.x);
            acc11.x = fmaf(-a01.w, b01.w, acc11.x);
            acc11.y = fmaf( a01.z, b01.w, acc11.y);
            acc11.y = fmaf( a01.w, b01.z, acc11.y);
        }
        if (k + 1 < d) {
            int nxt = cur ^ 1;
            Ash[nxt][i0s+0][mbs] = make_float2(apf.x, apf.y);
            Ash[nxt][i0s+1][mbs] = make_float2(apf.z, apf.w);
            *(float4*)&Bsh[nxt][io0] = bpf;
            __syncthreads();
        }
    }

    int mb0 = ty*2, mb1 = mb0 + 1;
    int mrow0 = m0 + (mb0 >> 3), b0 = mb0 & 7;
    int mrow1 = m0 + (mb1 >> 3), b1 = mb1 & 7;
    if (mrow0 < d) {
        size_t base = (size_t)(off + mrow0*d + n0)*256 + b0*32 + o0;
        *(float4*)(zc + base) = make_float4(acc00.x, acc00.y, acc01.x, acc01.y);
    }
    if (mrow1 < d) {
        size_t base = (size_t)(off + mrow1*d + n0)*256 + b1*32 + o0;
        *(float4*)(zc + base) = make_float4(acc10.x, acc10.y, acc11.x, acc11.y);
    }
}

// ---- fused scatter + n-DFT ----
// v5: fixed 16-iteration l-loop with 16 batched INDEPENDENT loads per nni
// (16-deep MLP). v4 was latency-bound: rolled dynamic l-loop = 1 outstanding
// zc load per wave (~250cyc serialized per iter). Invalid l (< lmin) clamps
// s to 0 (zc row 0 is L1-resident broadcast, ~free) with weight wsh==0.
// lmin/s are wave-uniform -> scalar cmp/select, SGPR-offset loads.
#define SU_DECL(G) float2 acc##G = {0.f, 0.f};
#define SU_UPD(G)  { float2 w = tw[(tbase + step*(G)) & 31]; \
    acc##G.x = fmaf( sv.x, w.x, acc##G.x); \
    acc##G.x = fmaf(-sv.y, w.y, acc##G.x); \
    acc##G.y = fmaf( sv.x, w.y, acc##G.y); \
    acc##G.y = fmaf( sv.y, w.x, acc##G.y); }
#define SU_ST(G)   up[G] = acc##G;
#define SU_ALL(X) X(0) X(1) X(2) X(3) X(4) X(5) X(6) X(7) \
                  X(8) X(9) X(10) X(11) X(12) X(13) X(14) X(15)
#define SU_LD(L) int s_##L = (L >= lmin) ? (c_OFF[L] + (m + L)*(2*(L) + 1) + (n + L)) : 0; \
    float2 zv_##L = zp[(size_t)s_##L * 256];
#define SU_FM(L) { float w = wrow[(L)*31]; \
    sv.x = fmaf(w, zv_##L.x, sv.x); sv.y = fmaf(w, zv_##L.y, sv.y); }

__global__ void __launch_bounds__(256) k_su(const float2* zc, const float* WsyT, float2* U) {
    __shared__ float wsh[496];      // [l*31 + nn]
    __shared__ float2 tw[32];
    int blk = blockIdx.x;           // (mmi*32 + j)*2 + half
    int half = blk & 1;
    int mj = blk >> 1;
    int mmi = mj >> 5, j = mj & 31;
    int g0 = half << 4;             // 0 or 16
    int m = mmi - 15;
    int am = m < 0 ? -m : m;
    for (int t = threadIdx.x; t < 496; t += 256) {
        int l = t / 31, nn = t - l*31;
        int n = nn - 15, an = n < 0 ? -n : n;
        float w = 0.f;
        if (l >= am && l >= an) {
            int s = c_OFF[l] + (m + l)*(2*l + 1) + (n + l);
            w = WsyT[(size_t)j*5456 + s];
        }
        wsh[t] = w;
    }
    if (threadIdx.x < 32) {
        float sn, cs;
        sincosf(2.0f*PI_F*(float)threadIdx.x/32.0f, &sn, &cs);
        tw[threadIdx.x] = make_float2(cs, sn);
    }
    __syncthreads();

    SU_ALL(SU_DECL)

    const float2* zp = zc + threadIdx.x;
    for (int nni = 0; nni < 31; ++nni) {
        int n = nni - 15, an = n < 0 ? -n : n;
        int lmin = am > an ? am : an;
        const float* wrow = wsh + nni;
        float2 sv = make_float2(0.f, 0.f);
        SU_ALL(SU_LD)
        SU_ALL(SU_FM)
        int step = (nni + 17) & 31;          // (nni-15) mod 32
        int tbase = (step * g0) & 31;        // twiddle index at g0
        SU_ALL(SU_UPD)
    }

    float2* up = U + (((size_t)j*256 + threadIdx.x)*31 + mmi)*32 + g0;
    SU_ALL(SU_ST)
}

// ---- out[b][o][a][j][g] = bias[o] + sum_m Re(U[j][bo][mm][g] e^{+2pi i m a/32}) ----
__global__ void __launch_bounds__(256) k_out(const float2* U, const float* bias, float* out) {
    __shared__ float2 Ush[992];       // [mm][g]
    __shared__ float2 tw[32];
    int blk = blockIdx.x;             // bo*32 + j
    int bo = blk >> 5, j = blk & 31;
    const float2* up = U + ((size_t)j*256 + bo)*992;
    for (int t = threadIdx.x; t < 992; t += 256) Ush[t] = up[t];
    if (threadIdx.x < 32) {
        float sn, cs;
        sincosf(2.0f*PI_F*(float)threadIdx.x/32.0f, &sn, &cs);
        tw[threadIdx.x] = make_float2(cs, sn);
    }
    __syncthreads();
    float bv = bias[bo & 31];
    int a  = threadIdx.x >> 3;         // 0..31
    int g0 = (threadIdx.x & 7) << 2;   // 0,4,...,28
    float ac0 = bv, ac1 = bv, ac2 = bv, ac3 = bv;
    for (int mmi = 0; mmi < 31; ++mmi) {
        int t = (((mmi + 17) & 31) * a) & 31;  // (m*a) mod 32
        float2 w = tw[t];
        const float2* ur = Ush + mmi*32 + g0;
        float2 u0 = ur[0], u1 = ur[1], u2 = ur[2], u3 = ur[3];
        ac0 += u0.x*w.x - u0.y*w.y;
        ac1 += u1.x*w.x - u1.y*w.y;
        ac2 += u2.x*w.x - u2.y*w.y;
        ac3 += u3.x*w.x - u3.y*w.y;
    }
    float4 res = make_float4(ac0, ac1, ac2, ac3);
    *(float4*)(out + (((size_t)bo*32 + a)*32 + j)*32 + g0) = res;
}

extern "C" void kernel_launch(void* const* d_in, const int* in_sizes, int n_in,
                              void* d_out, int out_size, void* d_ws, size_t ws_size,
                              hipStream_t stream) {
    const float* x    = (const float*)d_in[0];  // (8,16,64,64,64)
    const float* kern = (const float*)d_in[1];  // (16,32,72)
    const float* bias = (const float*)d_in[2];  // (32,)
    const float* ge   = (const float*)d_in[3];  // (72,3)
    float* out = (float*)d_out;                 // (8,32,32,32,32)
    char* ws = (char*)d_ws;

    float*  WsyT = (float*) (ws);                 // 32*5456 f32   =    698,368
    float2* zc   = (float2*)(ws +    698368);     // 5456*256 f2   = 11,173,888
    float2* U    = (float2*)(ws +  11872256);     // 8192*992 f2   = 65,011,712
    float*  WanT = (float*) (ws +  11872256);     // 64*5456 f32   =  1,396,736
    float2* D    = (float2*)(ws +  13268992);     // 5456*72  f2   =  3,142,656
    float2* yc   = (float2*)(ws +  16411648);     // 5456*512 f2   = 22,347,776
    float2* Fx   = (float2*)(ws +  38759424);     // 8192*496 f2   = 32,505,856
    float2* xc   = (float2*)(ws +  71265280);     // 5456*128 f2   =  5,586,944

    k_wigner_in  <<< 256, 256, 0, stream>>>(WanT);
    k_wigner_out <<< 128, 256, 0, stream>>>(WsyT);
    k_wigner_grid<<< 288, 256, 0, stream>>>(ge, D);
    k_yc         <<<1364, 256, 0, stream>>>(kern, D, yc);
    k_fft        <<<8192, 256, 0, stream>>>(x, Fx);
    k_xc         <<<3968, 256, 0, stream>>>(Fx, WanT, xc);  // 128 bf * 31 mm
    k_z          <<<1488, 256, 0, stream>>>(xc, yc, zc);    // ceil(d/4)*d blocks per l
    k_su         <<<1984, 256, 0, stream>>>(zc, WsyT, U);   // 31 mm * 32 j * 2 g-halves
    k_out        <<<8192, 256, 0, stream>>>(U, bias, out);  // 256 bo * 32 j
}

// Round 7
// 549.373 us; speedup vs baseline: 1.0934x; 1.0934x over previous
//
#include <hip/hip_runtime.h>
#include <math.h>

#define PI_D 3.141592653589793238462643383279502884
#define PI_F 3.14159265358979323846f
#define SCALING_F (1.0f/12.0f)

// off[l] = sum_{j<l}(2j+1)^2
__constant__ int c_OFF[17] = {0,1,10,35,84,165,286,455,680,969,1330,1771,2300,2925,3654,4495,5456};
// cumulative blocks for k_z: per l: ceil(d/4)*d
__constant__ int c_Z4[17] = {0,1,4,14,28,55,88,140,200,285,380,506,644,819,1008,1240,1488};

__device__ __forceinline__ void s_to_lmn(int s, int& l, int& m, int& n) {
    int ll = 15;
    while (s < c_OFF[ll]) --ll;
    int r = s - c_OFF[ll];
    int d = 2*ll + 1;
    l = ll;
    m = r / d - ll;
    n = r % d - ll;
}

// parallel table build: thread i (<64) fills entry i
__device__ __forceinline__ void build_tables_par(double beta, double* lf, double* cp, double* sp) {
    if (threadIdx.x < 64) {
        int i = threadIdx.x;
        lf[i] = lgamma((double)(i + 1));           // log(i!)
        double cb = cos(beta*0.5), sb = sin(beta*0.5);
        cp[i] = (i == 0) ? 1.0 : exp((double)i * log(cb));
        sp[i] = (i == 0) ? 1.0 : exp((double)i * log(sb));
    }
}

__device__ double wigner_d_dev(int l, int m, int n,
                               const double* lf, const double* cp, const double* sp) {
    int kmin = m - n; if (kmin < 0) kmin = 0;
    int kmax = l + m; { int k2 = l - n; if (k2 < kmax) kmax = k2; }
    double pref = 0.5*(lf[l+m] + lf[l-m] + lf[l+n] + lf[l-n]);
    double acc = 0.0;
    for (int k = kmin; k <= kmax; ++k) {
        double lg = pref - (lf[k] + lf[l+m-k] + lf[l-n-k] + lf[n-m+k]);
        double t = exp(lg) * cp[2*l + m - n - 2*k] * sp[n - m + 2*k];
        acc += (k & 1) ? -t : t;
    }
    return acc;
}

// ---- Wigner tables (transposed: W[j][s] for coalesced consumer reads) ----
__global__ void __launch_bounds__(256) k_wigner_in(float* WanT) {
    __shared__ double lf[64], cp[64], sp[64];
    __shared__ double tsum[32];
    __shared__ double wq;
    int j = blockIdx.x >> 2;        // 0..63
    int chunk = blockIdx.x & 3;
    double beta = PI_D * (2*j + 1) / 128.0;   // 4*B_IN = 128
    build_tables_par(beta, lf, cp, sp);
    if (threadIdx.x >= 64 && threadIdx.x < 96) {
        int k = threadIdx.x - 64;
        tsum[k] = sin((double)(2*j+1)*(2*k+1)*PI_D/128.0) / (double)(2*k+1);
    }
    __syncthreads();
    if (threadIdx.x == 0) {
        double inner = 0.0;
        for (int k = 0; k < 32; ++k) inner += tsum[k];
        wq = (2.0/32.0) * sin(PI_D*(2*j+1)/128.0) * inner / 4096.0; // /(2b)^2
    }
    __syncthreads();
    int s0 = chunk*1364, s1 = s0 + 1364; if (s1 > 5456) s1 = 5456;
    for (int s = s0 + threadIdx.x; s < s1; s += 256) {
        int l, m, n; s_to_lmn(s, l, m, n);
        WanT[j*5456 + s] = (float)(wigner_d_dev(l, m, n, lf, cp, sp) * wq);
    }
}

__global__ void __launch_bounds__(256) k_wigner_out(float* WsyT) {
    __shared__ double lf[64], cp[64], sp[64];
    int j = blockIdx.x >> 2;        // 0..31
    int chunk = blockIdx.x & 3;
    build_tables_par(PI_D*(2*j+1)/64.0, lf, cp, sp); // 4*B_OUT=64
    __syncthreads();
    int s0 = chunk*1364, s1 = s0 + 1364; if (s1 > 5456) s1 = 5456;
    for (int s = s0 + threadIdx.x; s < s1; s += 256) {
        int l, m, n; s_to_lmn(s, l, m, n);
        WsyT[j*5456 + s] = (float)(wigner_d_dev(l, m, n, lf, cp, sp) * (double)(2*l+1));
    }
}

__global__ void __launch_bounds__(256) k_wigner_grid(const float* ge, float2* D) {
    __shared__ double lf[64], cp[64], sp[64];
    int g = blockIdx.x >> 2;        // 0..71
    int chunk = blockIdx.x & 3;
    double beta = (double)ge[g*3 + 1];
    double alp  = (double)ge[g*3 + 0];
    double gam  = (double)ge[g*3 + 2];
    build_tables_par(beta, lf, cp, sp);
    __syncthreads();
    int s0 = chunk*1364, s1 = s0 + 1364; if (s1 > 5456) s1 = 5456;
    for (int s = s0 + threadIdx.x; s < s1; s += 256) {
        int l, m, n; s_to_lmn(s, l, m, n);
        double dv = wigner_d_dev(l, m, n, lf, cp, sp);
        double th = m*alp + n*gam;
        double sn, cs; sincos(th, &sn, &cs);
        D[s*72 + g] = make_float2((float)(dv*cs), (float)(-dv*sn));
    }
}

// ---- yc[s][io] = SCALING * sum_g kernel[io][g] * D[s][g]; 4 s per block ----
__global__ void __launch_bounds__(256) k_yc(const float* kern, const float2* D, float2* yc) {
    __shared__ float2 Ds[4][72];
    int s0 = blockIdx.x * 4;
    for (int t = threadIdx.x; t < 288; t += 256) {
        int ss = t / 72, g = t - ss*72;
        Ds[ss][g] = D[(size_t)(s0 + ss)*72 + g];
    }
    __syncthreads();
    for (int io = threadIdx.x; io < 512; io += 256) {
        const float* kp = kern + io*72;
        float2 a0 = {0,0}, a1 = {0,0}, a2 = {0,0}, a3 = {0,0};
        for (int g = 0; g < 72; ++g) {
            float kv = kp[g];
            a0.x = fmaf(kv, Ds[0][g].x, a0.x); a0.y = fmaf(kv, Ds[0][g].y, a0.y);
            a1.x = fmaf(kv, Ds[1][g].x, a1.x); a1.y = fmaf(kv, Ds[1][g].y, a1.y);
            a2.x = fmaf(kv, Ds[2][g].x, a2.x); a2.y = fmaf(kv, Ds[2][g].y, a2.y);
            a3.x = fmaf(kv, Ds[3][g].x, a3.x); a3.y = fmaf(kv, Ds[3][g].y, a3.y);
        }
        yc[(size_t)(s0+0)*512 + io] = make_float2(a0.x*SCALING_F, a0.y*SCALING_F);
        yc[(size_t)(s0+1)*512 + io] = make_float2(a1.x*SCALING_F, a1.y*SCALING_F);
        yc[(size_t)(s0+2)*512 + io] = make_float2(a2.x*SCALING_F, a2.y*SCALING_F);
        yc[(size_t)(s0+3)*512 + io] = make_float2(a3.x*SCALING_F, a3.y*SCALING_F);
    }
}

// ---- forward 2D partial DFT per (b,f,j): Fx[bf][j][mm 0..30][nn 0..15] ----
// v4: stage 1 as radix-4 DIF (kept from round 6: ~10us gain; 64 LDS ops vs 160).
#define FFT_YD(I) float y0_##I, y2_##I, y1r_##I, y1i_##I;
#define FFT_YD_ALL FFT_YD(0) FFT_YD(1) FFT_YD(2) FFT_YD(3) FFT_YD(4) FFT_YD(5) \
    FFT_YD(6) FFT_YD(7) FFT_YD(8) FFT_YD(9) FFT_YD(10) FFT_YD(11) FFT_YD(12) \
    FFT_YD(13) FFT_YD(14) FFT_YD(15)
#define FFT_YB(E,O) { \
    float2 xa = *(const float2*)&xs[a][E]; \
    float2 xb = *(const float2*)&xs[a][(E)+16]; \
    float2 xc2 = *(const float2*)&xs[a][(E)+32]; \
    float2 xd = *(const float2*)&xs[a][(E)+48]; \
    float s02 = xa.x + xc2.x, d02 = xa.x - xc2.x; \
    float s13 = xb.x + xd.x, d13 = xb.x - xd.x; \
    y0_##E = s02 + s13; y2_##E = s02 - s13; y1r_##E = d02; y1i_##E = -d13; \
    s02 = xa.y + xc2.y; d02 = xa.y - xc2.y; \
    s13 = xb.y + xd.y; d13 = xb.y - xd.y; \
    y0_##O = s02 + s13; y2_##O = s02 - s13; y1r_##O = d02; y1i_##O = -d13; \
}
#define FFT_A0(E,O) { float4 w = *(const float4*)&t0[E]; \
    c0.x = fmaf(y0_##E, w.x, c0.x); c0.y = fmaf(y0_##E, w.y, c0.y); \
    c0.x = fmaf(y0_##O, w.z, c0.x); c0.y = fmaf(y0_##O, w.w, c0.y); }
#define FFT_A2(E,O) { float4 w = *(const float4*)&t2[E]; \
    c2.x = fmaf(y2_##E, w.x, c2.x); c2.y = fmaf(y2_##E, w.y, c2.y); \
    c2.x = fmaf(y2_##O, w.z, c2.x); c2.y = fmaf(y2_##O, w.w, c2.y); }
#define FFT_A1(E,O) { float4 w = *(const float4*)&t1[E]; \
    c1.x = fmaf(y1r_##E, w.x, c1.x); c1.x = fmaf(-y1i_##E, w.y, c1.x); \
    c1.y = fmaf(y1r_##E, w.y, c1.y); c1.y = fmaf(y1i_##E, w.x, c1.y); \
    c1.x = fmaf(y1r_##O, w.z, c1.x); c1.x = fmaf(-y1i_##O, w.w, c1.x); \
    c1.y = fmaf(y1r_##O, w.w, c1.y); c1.y = fmaf(y1i_##O, w.z, c1.y); }
#define FFT_A3(E,O) { float4 w = *(const float4*)&t3[E]; \
    c3.x = fmaf(y1r_##E, w.x, c3.x); c3.x = fmaf(y1i_##E, w.y, c3.x); \
    c3.y = fmaf(y1r_##E, w.y, c3.y); c3.y = fmaf(-y1i_##E, w.x, c3.y); \
    c3.x = fmaf(y1r_##O, w.z, c3.x); c3.x = fmaf(y1i_##O, w.w, c3.x); \
    c3.y = fmaf(y1r_##O, w.w, c3.y); c3.y = fmaf(-y1i_##O, w.z, c3.y); }
#define FFT_PAIRS(X) X(0,1) X(2,3) X(4,5) X(6,7) X(8,9) X(10,11) X(12,13) X(14,15)

__global__ void __launch_bounds__(256) k_fft(const float* x, float2* Fx) {
    __shared__ float  xs[64][66];    // pad 66: 2-way banks, 8B-aligned rows
    __shared__ float2 T1s[16][66];   // [nn][a], pad 66: 16B-aligned, distinct banks
    __shared__ float2 tw2[16][66];   // tw2[n][g]=e^{-2pi i n g/64}; pad 66
    int blk = blockIdx.x;            // bf*64 + j
    int bf = blk >> 6, j = blk & 63;
    const float* xp = x + (size_t)bf*262144 + j*64;  // x[b,f,a,j,g]
    for (int t = threadIdx.x; t < 1024; t += 256) {
        int a = t >> 4, g4 = (t & 15) << 2;
        float4 v = *(const float4*)(xp + (size_t)a*4096 + g4);
        *(float2*)&xs[a][g4]     = make_float2(v.x, v.y);
        *(float2*)&xs[a][g4 + 2] = make_float2(v.z, v.w);
    }
    for (int t = threadIdx.x; t < 1024; t += 256) {
        int n = t >> 6, g = t & 63;
        float sn, cs;
        sincosf(-2.0f*PI_F*(float)((n*g) & 63)/64.0f, &sn, &cs);
        tw2[n][g] = make_float2(cs, sn);
    }
    __syncthreads();
    // stage 1 (radix-4 DIF): T1[n] = sum_{g1<16} tw2[n][g1] * y_{n&3}[g1]
    {
        int a  = threadIdx.x & 63;
        int n0 = (threadIdx.x >> 6) << 2;
        FFT_YD_ALL
        FFT_PAIRS(FFT_YB)
        float2 c0 = {0,0}, c1 = {0,0}, c2 = {0,0}, c3 = {0,0};
        const float2* t0 = tw2[n0];
        const float2* t1 = tw2[n0 + 1];
        const float2* t2 = tw2[n0 + 2];
        const float2* t3 = tw2[n0 + 3];
        FFT_PAIRS(FFT_A0)
        FFT_PAIRS(FFT_A1)
        FFT_PAIRS(FFT_A2)
        FFT_PAIRS(FFT_A3)
        T1s[n0    ][a] = c0;
        T1s[n0 + 1][a] = c1;
        T1s[n0 + 2][a] = c2;
        T1s[n0 + 3][a] = c3;
    }
    __syncthreads();
    // stage 2: Fx[mm][nn] = sum_a T1[nn][a] e^{-2pi i (mm-15) a/64}; thread = (nn, 2mm)
    {
        int nn = threadIdx.x & 15, mmg = threadIdx.x >> 4;
        int mm0 = mmg*2, mm1 = mm0 + 1;
        int am0 = mm0 >= 15 ? mm0 - 15 : 15 - mm0;
        int am1 = mm1 >= 15 ? mm1 - 15 : 15 - mm1;
        if (am1 > 15) am1 = 15;                 // pad slot mm=31, discarded
        float sg0 = mm0 >= 15 ? 1.f : -1.f;     // conj for negative m
        float sg1 = mm1 >= 15 ? 1.f : -1.f;
        float2 c0 = {0,0}, c1 = {0,0};
        for (int a = 0; a < 64; a += 2) {
            float4 t01 = *(const float4*)&T1s[nn][a];     // T1[a], T1[a+1]
            float4 wa  = *(const float4*)&tw2[am0][a];    // rows 8..15: distinct bank groups
            float4 wb  = *(const float4*)&tw2[am1][a];
            float way0 = wa.y*sg0, way1 = wa.w*sg0;
            float wby0 = wb.y*sg1, wby1 = wb.w*sg1;
            c0.x += t01.x*wa.x - t01.y*way0;
            c0.y += t01.x*way0 + t01.y*wa.x;
            c0.x += t01.z*wa.z - t01.w*way1;
            c0.y += t01.z*way1 + t01.w*wa.z;
            c1.x += t01.x*wb.x - t01.y*wby0;
            c1.y += t01.x*wby0 + t01.y*wb.x;
            c1.x += t01.z*wb.z - t01.w*wby1;
            c1.y += t01.z*wby1 + t01.w*wb.z;
        }
        float2* outp = Fx + (size_t)blk*496;
        outp[mm0*16 + nn] = c0;
        if (mm1 < 31) outp[mm1*16 + nn] = c1;
    }
}

// ---- xc[s][bf] = sum_j WanT[j][s] * F(m(s),n(s)); block = (bf, mm) ----
__global__ void __launch_bounds__(256) k_xc(const float2* Fx, const float* WanT, float2* xc) {
    __shared__ float2 Fsh[31][65];   // [n+15][j]
    int blk = blockIdx.x;            // bf*31 + mm
    int bf = blk / 31, mm = blk - bf*31;
    int m = mm - 15;
    const float2* fp = Fx + (size_t)bf * 64 * 496;
    for (int t = threadIdx.x; t < 1024; t += 256) {   // n >= 0 from slice mm
        int j = t >> 4, nn = t & 15;
        Fsh[nn + 15][j] = fp[j*496 + mm*16 + nn];
    }
    for (int t = threadIdx.x; t < 1024; t += 256) {   // n < 0: conj of slice 30-mm
        int j = t >> 4, nn = t & 15;
        if (nn > 0) {
            float2 v = fp[j*496 + (30 - mm)*16 + nn];
            Fsh[15 - nn][j] = make_float2(v.x, -v.y);
        }
    }
    __syncthreads();
    int am = m < 0 ? -m : m;
    int q = threadIdx.x;
    int l = am;
    while (l <= 15 && q >= 2*l + 1) { q -= 2*l + 1; ++l; }
    if (l <= 15) {
        int n = q - l;
        int d = 2*l + 1;
        int s = c_OFF[l] + (m + l)*d + (n + l);
        const float* wp = WanT + s;
        const float2* frow = Fsh[n + 15];
        float ar = 0.f, ai = 0.f;
        for (int j2 = 0; j2 < 64; ++j2) {
            float w = wp[(size_t)j2*5456];
            ar = fmaf(w, frow[j2].x, ar);
            ai = fmaf(w, frow[j2].y, ai);
        }
        xc[(size_t)s*128 + bf] = make_float2(ar, ai);
    }
}

// ---- per-l complex GEMM: z[(m,b),(n,o)] = sum_{k,i} X[(m,b),(k,i)] Y[(k,i),(n,o)] ----
__global__ void __launch_bounds__(256) k_z(const float2* xc, const float2* yc, float2* zc) {
    __shared__ float2 Ash[2][16][34];   // [buf][i][mb(32)+pad]
    __shared__ float2 Bsh[2][512];      // [buf][io]
    int blk = 1487 - blockIdx.x;        // heavy l first
    int l = 0;
    while (l < 15 && blk >= c_Z4[l+1]) ++l;
    int r = blk - c_Z4[l];
    int d = 2*l + 1;
    int mt = r / d;
    int n0 = r - mt*d;
    int m0 = mt*4;
    int off = c_OFF[l];

    int tx = threadIdx.x & 15, ty = threadIdx.x >> 4;   // ty 0..15
    int o0 = tx*2;

    // staging: thread loads one float4 of A (2 consecutive bf of its row) + one of B
    int mloc_s = threadIdx.x >> 6;            // 0..3
    int bf0    = (threadIdx.x & 63) << 1;     // 0,2,...,126 (even: both halves same b)
    int bs     = bf0 >> 4;                    // b 0..7
    int i0s    = bf0 & 15;                    // even i
    int mbs    = mloc_s*8 + bs;
    int mrow_s = m0 + mloc_s; if (mrow_s > d-1) mrow_s = d-1;
    const float2* xrow = xc + (size_t)(off + mrow_s*d)*128 + bf0;   // k stride: +128
    int io0 = threadIdx.x * 2;
    const float2* yrow = yc + (size_t)(off + n0)*512 + io0;         // k stride: +d*512

    float4 apf, bpf;
    apf = *(const float4*)(xrow);
    bpf = *(const float4*)(yrow);
    Ash[0][i0s+0][mbs] = make_float2(apf.x, apf.y);
    Ash[0][i0s+1][mbs] = make_float2(apf.z, apf.w);
    *(float4*)&Bsh[0][io0] = bpf;
    __syncthreads();

    float2 acc00 = {0.f,0.f}, acc01 = {0.f,0.f}, acc10 = {0.f,0.f}, acc11 = {0.f,0.f};

    for (int k = 0; k < d; ++k) {
        int cur = k & 1;
        if (k + 1 < d) {
            apf = *(const float4*)(xrow + (size_t)(k+1)*128);
            bpf = *(const float4*)(yrow + (size_t)(k+1)*d*512);
        }
        #pragma unroll
        for (int i = 0; i < 16; ++i) {
            float4 a01 = *(const float4*)&Ash[cur][i][ty*2];      // mb=2ty, 2ty+1
            float4 b01 = *(const float4*)&Bsh[cur][i*32 + o0];    // o=o0, o0+1
            acc00.x = fmaf( a01.x, b01.x, acc00.x);
            acc00.x = fmaf(-a01.y, b01.y, acc00.x);
            acc00.y = fmaf( a01.x, b01.y, acc00.y);
            acc00.y = fmaf( a01.y, b01.x, acc00.y);
            acc01.x = fmaf( a01.x, b01.z, acc01.x);
            acc01.x = fmaf(-a01.y, b01.w, acc01.x);
            acc01.y = fmaf( a01.x, b01.w, acc01.y);
            acc01.y = fmaf( a01.y, b01.z, acc01.y);
            acc10.x = fmaf( a01.z, b01.x, acc10.x);
            acc10.x = fmaf(-a01.w, b01.y, acc10.x);
            acc10.y = fmaf( a01.z, b01.y, acc10.y);
            acc10.y = fmaf( a01.w, b01.x, acc10.y);
            acc11.x = fmaf( a01.z, b01.z, acc11.x);
            acc11.x = fmaf(-a01.w, b01.w, acc11.x);
            acc11.y = fmaf( a01.z, b01.w, acc11.y);
            acc11.y = fmaf( a01.w, b01.z, acc11.y);
        }
        if (k + 1 < d) {
            int nxt = cur ^ 1;
            Ash[nxt][i0s+0][mbs] = make_float2(apf.x, apf.y);
            Ash[nxt][i0s+1][mbs] = make_float2(apf.z, apf.w);
            *(float4*)&Bsh[nxt][io0] = bpf;
            __syncthreads();
        }
    }

    int mb0 = ty*2, mb1 = mb0 + 1;
    int mrow0 = m0 + (mb0 >> 3), b0 = mb0 & 7;
    int mrow1 = m0 + (mb1 >> 3), b1 = mb1 & 7;
    if (mrow0 < d) {
        size_t base = (size_t)(off + mrow0*d + n0)*256 + b0*32 + o0;
        *(float4*)(zc + base) = make_float4(acc00.x, acc00.y, acc01.x, acc01.y);
    }
    if (mrow1 < d) {
        size_t base = (size_t)(off + mrow1*d + n0)*256 + b1*32 + o0;
        *(float4*)(zc + base) = make_float4(acc10.x, acc10.y, acc11.x, acc11.y);
    }
}

// ---- fused scatter + n-DFT ----
// v6: v4's rolled dynamic l-loop REVERTED (v5's fixed-16 batch was +36us:
// 32 in-flight regs forced AGPR staging, +45% VMEM, +50% VALU), plus chunk-4
// MLP: 4 independent zc loads in flight per chunk (8 VGPRs), wave-uniform
// bounds, tail loop for remainder. No clamped dummy loads.
#define SU_DECL(G) float2 acc##G = {0.f, 0.f};
#define SU_UPD(G)  { float2 w = tw[(tbase + step*(G)) & 31]; \
    acc##G.x = fmaf( sv.x, w.x, acc##G.x); \
    acc##G.x = fmaf(-sv.y, w.y, acc##G.x); \
    acc##G.y = fmaf( sv.x, w.y, acc##G.y); \
    acc##G.y = fmaf( sv.y, w.x, acc##G.y); }
#define SU_ST(G)   up[G] = acc##G;
#define SU_ALL(X) X(0) X(1) X(2) X(3) X(4) X(5) X(6) X(7) \
                  X(8) X(9) X(10) X(11) X(12) X(13) X(14) X(15)

__global__ void __launch_bounds__(256) k_su(const float2* zc, const float* WsyT, float2* U) {
    __shared__ float wsh[496];      // [l*31 + nn]
    __shared__ float2 tw[32];
    int blk = blockIdx.x;           // (mmi*32 + j)*2 + half
    int half = blk & 1;
    int mj = blk >> 1;
    int mmi = mj >> 5, j = mj & 31;
    int g0 = half << 4;             // 0 or 16
    int m = mmi - 15;
    int am = m < 0 ? -m : m;
    for (int t = threadIdx.x; t < 496; t += 256) {
        int l = t / 31, nn = t - l*31;
        int n = nn - 15, an = n < 0 ? -n : n;
        float w = 0.f;
        if (l >= am && l >= an) {
            int s = c_OFF[l] + (m + l)*(2*l + 1) + (n + l);
            w = WsyT[(size_t)j*5456 + s];
        }
        wsh[t] = w;
    }
    if (threadIdx.x < 32) {
        float sn, cs;
        sincosf(2.0f*PI_F*(float)threadIdx.x/32.0f, &sn, &cs);
        tw[threadIdx.x] = make_float2(cs, sn);
    }
    __syncthreads();

    SU_ALL(SU_DECL)

    const float2* zp = zc + threadIdx.x;
    for (int nni = 0; nni < 31; ++nni) {
        int n = nni - 15, an = n < 0 ? -n : n;
        int lmin = am > an ? am : an;
        const float* wrow = wsh + nni;
        float2 sv = make_float2(0.f, 0.f);
        int l = lmin;
        for (; l + 3 <= 15; l += 4) {
            int s0 = c_OFF[l]     + (m + l    )*(2*l + 1) + (n + l);
            int s1 = c_OFF[l + 1] + (m + l + 1)*(2*l + 3) + (n + l + 1);
            int s2 = c_OFF[l + 2] + (m + l + 2)*(2*l + 5) + (n + l + 2);
            int s3 = c_OFF[l + 3] + (m + l + 3)*(2*l + 7) + (n + l + 3);
            float2 z0 = zp[(size_t)s0 * 256];
            float2 z1 = zp[(size_t)s1 * 256];
            float2 z2 = zp[(size_t)s2 * 256];
            float2 z3 = zp[(size_t)s3 * 256];
            float w0 = wrow[l*31], w1 = wrow[(l+1)*31];
            float w2 = wrow[(l+2)*31], w3 = wrow[(l+3)*31];
            sv.x = fmaf(w0, z0.x, sv.x); sv.y = fmaf(w0, z0.y, sv.y);
            sv.x = fmaf(w1, z1.x, sv.x); sv.y = fmaf(w1, z1.y, sv.y);
            sv.x = fmaf(w2, z2.x, sv.x); sv.y = fmaf(w2, z2.y, sv.y);
            sv.x = fmaf(w3, z3.x, sv.x); sv.y = fmaf(w3, z3.y, sv.y);
        }
        for (; l <= 15; ++l) {
            int s = c_OFF[l] + (m + l)*(2*l + 1) + (n + l);
            float2 zv = zp[(size_t)s * 256];
            float w = wrow[l*31];
            sv.x = fmaf(w, zv.x, sv.x);
            sv.y = fmaf(w, zv.y, sv.y);
        }
        int step = (nni + 17) & 31;          // (nni-15) mod 32
        int tbase = (step * g0) & 31;        // twiddle index at g0
        SU_ALL(SU_UPD)
    }

    float2* up = U + (((size_t)j*256 + threadIdx.x)*31 + mmi)*32 + g0;
    SU_ALL(SU_ST)
}

// ---- out[b][o][a][j][g] = bias[o] + sum_m Re(U[j][bo][mm][g] e^{+2pi i m a/32}) ----
__global__ void __launch_bounds__(256) k_out(const float2* U, const float* bias, float* out) {
    __shared__ float2 Ush[992];       // [mm][g]
    __shared__ float2 tw[32];
    int blk = blockIdx.x;             // bo*32 + j
    int bo = blk >> 5, j = blk & 31;
    const float2* up = U + ((size_t)j*256 + bo)*992;
    for (int t = threadIdx.x; t < 992; t += 256) Ush[t] = up[t];
    if (threadIdx.x < 32) {
        float sn, cs;
        sincosf(2.0f*PI_F*(float)threadIdx.x/32.0f, &sn, &cs);
        tw[threadIdx.x] = make_float2(cs, sn);
    }
    __syncthreads();
    float bv = bias[bo & 31];
    int a  = threadIdx.x >> 3;         // 0..31
    int g0 = (threadIdx.x & 7) << 2;   // 0,4,...,28
    float ac0 = bv, ac1 = bv, ac2 = bv, ac3 = bv;
    for (int mmi = 0; mmi < 31; ++mmi) {
        int t = (((mmi + 17) & 31) * a) & 31;  // (m*a) mod 32
        float2 w = tw[t];
        const float2* ur = Ush + mmi*32 + g0;
        float2 u0 = ur[0], u1 = ur[1], u2 = ur[2], u3 = ur[3];
        ac0 += u0.x*w.x - u0.y*w.y;
        ac1 += u1.x*w.x - u1.y*w.y;
        ac2 += u2.x*w.x - u2.y*w.y;
        ac3 += u3.x*w.x - u3.y*w.y;
    }
    float4 res = make_float4(ac0, ac1, ac2, ac3);
    *(float4*)(out + (((size_t)bo*32 + a)*32 + j)*32 + g0) = res;
}

extern "C" void kernel_launch(void* const* d_in, const int* in_sizes, int n_in,
                              void* d_out, int out_size, void* d_ws, size_t ws_size,
                              hipStream_t stream) {
    const float* x    = (const float*)d_in[0];  // (8,16,64,64,64)
    const float* kern = (const float*)d_in[1];  // (16,32,72)
    const float* bias = (const float*)d_in[2];  // (32,)
    const float* ge   = (const float*)d_in[3];  // (72,3)
    float* out = (float*)d_out;                 // (8,32,32,32,32)
    char* ws = (char*)d_ws;

    float*  WsyT = (float*) (ws);                 // 32*5456 f32   =    698,368
    float2* zc   = (float2*)(ws +    698368);     // 5456*256 f2   = 11,173,888
    float2* U    = (float2*)(ws +  11872256);     // 8192*992 f2   = 65,011,712
    float*  WanT = (float*) (ws +  11872256);     // 64*5456 f32   =  1,396,736
    float2* D    = (float2*)(ws +  13268992);     // 5456*72  f2   =  3,142,656
    float2* yc   = (float2*)(ws +  16411648);     // 5456*512 f2   = 22,347,776
    float2* Fx   = (float2*)(ws +  38759424);     // 8192*496 f2   = 32,505,856
    float2* xc   = (float2*)(ws +  71265280);     // 5456*128 f2   =  5,586,944

    k_wigner_in  <<< 256, 256, 0, stream>>>(WanT);
    k_wigner_out <<< 128, 256, 0, stream>>>(WsyT);
    k_wigner_grid<<< 288, 256, 0, stream>>>(ge, D);
    k_yc         <<<1364, 256, 0, stream>>>(kern, D, yc);
    k_fft        <<<8192, 256, 0, stream>>>(x, Fx);
    k_xc         <<<3968, 256, 0, stream>>>(Fx, WanT, xc);  // 128 bf * 31 mm
    k_z          <<<1488, 256, 0, stream>>>(xc, yc, zc);    // ceil(d/4)*d blocks per l
    k_su         <<<1984, 256, 0, stream>>>(zc, WsyT, U);   // 31 mm * 32 j * 2 g-halves
    k_out        <<<8192, 256, 0, stream>>>(U, bias, out);  // 256 bo * 32 j
}